// Round 1
// baseline (9892.205 us; speedup 1.0000x reference)
//
#include <hip/hip_runtime.h>
#include <math.h>

#define TSTEPS 512
#define BN 4096
#define NBLK 256
#define NTHR 256
#define NPB 16        // neurons per block (BN/NBLK)
#define NPARTS 64     // NTHR/4 lanes-per-part
#define CPP 64        // columns per part (BN/NPARTS)

typedef unsigned long long u64;

__device__ __forceinline__ u64 ld_agent(const u64* p) {
    return __hip_atomic_load(p, __ATOMIC_RELAXED, __HIP_MEMORY_SCOPE_AGENT);
}
__device__ __forceinline__ void st_agent(u64* p, u64 v) {
    __hip_atomic_store(p, v, __ATOMIC_RELAXED, __HIP_MEMORY_SCOPE_AGENT);
}

// Persistent kernel: 256 blocks (<=1 per CU, always co-resident: LDS 37KB -> >=4 blk/CU cap),
// lock-free tagged spike exchange, per-neuron state held in registers of threads tid<16.
template<bool TR>
__global__ __launch_bounds__(NTHR, 1)
void glif_kernel(const float* __restrict__ x_seq, const float* __restrict__ w,
                 const float* __restrict__ b_in, const float* __restrict__ v0,
                 const float* __restrict__ Ia0, const float* __restrict__ vth_in,
                 const float* __restrict__ vrst_in, const float* __restrict__ vrest_in,
                 const float* __restrict__ cm_in, const float* __restrict__ tau_in,
                 const float* __restrict__ k_in, const float* __restrict__ asc_in,
                 const float* __restrict__ mask_in,
                 float* __restrict__ out_s, float* __restrict__ out_v,
                 float* __restrict__ out_vf, float* __restrict__ out_if,
                 u64* __restrict__ sbuf, unsigned* __restrict__ bar,
                 float* __restrict__ wT)
{
    __shared__ float s_lds[NPARTS * 65];     // padded: col j at [(j>>6)*65 + (j&63)]
    __shared__ float4 partial[NPARTS][4];
    __shared__ float tile[64][65];           // transpose staging

    const int blk = blockIdx.x;
    const int tid = threadIdx.x;
    const int part = tid >> 2;
    const int q = tid & 3;
    const int n0 = blk * NPB;

    // ---- Phase 0: transpose w (row-major) -> wT so active columns are contiguous rows
    if (TR) {
        for (int tt = 0; tt < 16; ++tt) {
            int tile_id = blk + tt * NBLK;       // 4096 tiles of 64x64, 16 per block
            int ti = tile_id >> 6, tj = tile_id & 63;
            int c = tid & 63, r0 = tid >> 6;
#pragma unroll
            for (int rr = 0; rr < 16; ++rr) {
                int r = r0 + rr * 4;
                tile[r][c] = w[(size_t)(ti * 64 + r) * BN + tj * 64 + c];
            }
            __syncthreads();
            int rw = tid & 63, c0 = tid >> 6;
#pragma unroll
            for (int cc = 0; cc < 16; ++cc) {
                int cw = c0 + cc * 4;
                wT[(size_t)(tj * 64 + cw) * BN + ti * 64 + rw] = tile[rw][cw];
            }
            __syncthreads();
        }
    }

    // ---- single grid barrier: all blocks must see completed wT before step loop
    __syncthreads();
    if (tid == 0) {
        __threadfence();
        __hip_atomic_fetch_add(bar, 1u, __ATOMIC_ACQ_REL, __HIP_MEMORY_SCOPE_AGENT);
        while (__hip_atomic_load(bar, __ATOMIC_RELAXED, __HIP_MEMORY_SCOPE_AGENT) < NBLK) {
            __builtin_amdgcn_s_sleep(8);
        }
        __threadfence();
    }
    __syncthreads();

    // ---- per-neuron state in registers (threads tid<NPB own neuron n)
    const int n = n0 + tid;
    float v = 0, I0 = 0, I1 = 0, bb = 0, aa = 0, bd0 = 0, bd1 = 0, as0 = 0, as1 = 0,
          vth = 0, vrst = 0, vrest = 0, cm = 1, tau = 1, msk = 0;
    if (tid < NPB) {
        v = v0[n]; I0 = Ia0[2 * n]; I1 = Ia0[2 * n + 1];
        bb = b_in[n]; vth = vth_in[n]; vrst = vrst_in[n]; vrest = vrest_in[n];
        cm = cm_in[n]; tau = tau_in[n]; msk = mask_in[n];
        // match jnp.exp(-DT/tau): fp32 divide, then correctly-rounded exp via double
        aa  = (float)exp((double)(-1.0f / tau));
        bd0 = (float)exp((double)(-k_in[2 * n]));
        bd1 = (float)exp((double)(-k_in[2 * n + 1]));
        as0 = asc_in[2 * n]; as1 = asc_in[2 * n + 1];
    }

    for (int t = 0; t < TSTEPS; ++t) {
        float xt = 0.0f;
        if (tid < NPB) xt = x_seq[(size_t)t * BN + n];   // prefetch, used after GEMV

        // ---- stage spikes of step t-1 (tag == t; tag 0 + value 0 from memset = initial zeros)
        const u64* src = sbuf + (size_t)((t + 1) & 1) * BN;
        const u64 want = (u64)t;
        u64 ev[16];
#pragma unroll
        for (int r = 0; r < 16; ++r) ev[r] = ld_agent(&src[tid + r * NTHR]);  // batch-issue
#pragma unroll
        for (int r = 0; r < 16; ++r) {
            int i = tid + r * NTHR;
            u64 e = ev[r];
            while ((e >> 32) != want) {
                __builtin_amdgcn_s_sleep(2);
                e = ld_agent(&src[i]);
            }
            s_lds[(i >> 6) * 65 + (i & 63)] = __uint_as_float((unsigned)e);
        }
        __syncthreads();

        // ---- sparse GEMV: lin[n] = sum over active columns j of w[n][j]*s[j]
        float ax = 0.f, ay = 0.f, az = 0.f, aw = 0.f;
        const float* sp = &s_lds[part * 65];
        if (TR) {
            const float* wbase = wT + (size_t)(part * CPP) * BN + n0 + q * 4;
#pragma unroll 8
            for (int jj = 0; jj < CPP; ++jj) {
                float sj = sp[jj];
                if (sj != 0.0f) {
                    const float4 wv = *reinterpret_cast<const float4*>(wbase + (size_t)jj * BN);
                    ax = fmaf(wv.x, sj, ax);
                    ay = fmaf(wv.y, sj, ay);
                    az = fmaf(wv.z, sj, az);
                    aw = fmaf(wv.w, sj, aw);
                }
            }
        } else {
            // fallback (workspace too small for wT): strided scalar reads of w rows
            const int nn = n0 + q * 4;
#pragma unroll 4
            for (int jj = 0; jj < CPP; ++jj) {
                float sj = sp[jj];
                if (sj != 0.0f) {
                    size_t base = (size_t)nn * BN + part * CPP + jj;
                    ax = fmaf(w[base], sj, ax);
                    ay = fmaf(w[base + BN], sj, ay);
                    az = fmaf(w[base + 2 * (size_t)BN], sj, az);
                    aw = fmaf(w[base + 3 * (size_t)BN], sj, aw);
                }
            }
        }
        partial[part][q] = make_float4(ax, ay, az, aw);
        __syncthreads();
#pragma unroll
        for (int st = 32; st >= 1; st >>= 1) {
            if (part < st) {
                float4 x1 = partial[part][q];
                float4 x2 = partial[part + st][q];
                x1.x += x2.x; x1.y += x2.y; x1.z += x2.z; x1.w += x2.w;
                partial[part][q] = x1;
            }
            __syncthreads();
        }

        // ---- neuron update (reference op order), publish spike with step tag
        if (tid < NPB) {
            float lin = reinterpret_cast<const float*>(partial)[tid];
            float x = (xt + bb) + lin;
            float Isum = I0 + I1;
            float vinf = vrest + (tau * (x + Isum)) / cm;
            float vp = vinf + (v - vinf) * aa;
            float u = (vp - vth) / (vth - vrst);
            float s = (u > 0.0f) ? msk : 0.0f;
            float vpost = vp - (vp - vrst) * s;       // HARD_RESET
            I0 = I0 * bd0 + as0 * s;
            I1 = I1 * bd1 + as1 * s;
            v = vpost;
            out_s[(size_t)t * BN + n] = s;
            out_v[(size_t)t * BN + n] = vpost;
            u64 ent = (((u64)(t + 1)) << 32) | (u64)__float_as_uint(s);
            st_agent(&sbuf[(size_t)(t & 1) * BN + n], ent);
        }
    }

    if (tid < NPB) {
        out_vf[n] = v;
        out_if[2 * n] = I0;
        out_if[2 * n + 1] = I1;
    }
}

extern "C" void kernel_launch(void* const* d_in, const int* in_sizes, int n_in,
                              void* d_out, int out_size, void* d_ws, size_t ws_size,
                              hipStream_t stream)
{
    const float* x_seq = (const float*)d_in[0];
    const float* w     = (const float*)d_in[1];
    const float* b     = (const float*)d_in[2];
    const float* v0    = (const float*)d_in[3];
    const float* Ia0   = (const float*)d_in[4];
    const float* vth   = (const float*)d_in[5];
    const float* vrst  = (const float*)d_in[6];
    const float* vrest = (const float*)d_in[7];
    const float* cm    = (const float*)d_in[8];
    const float* tau   = (const float*)d_in[9];
    const float* k     = (const float*)d_in[10];
    const float* asc   = (const float*)d_in[11];
    const float* mask  = (const float*)d_in[12];

    float* out_s  = (float*)d_out;
    float* out_v  = out_s + (size_t)TSTEPS * BN;
    float* out_vf = out_v + (size_t)TSTEPS * BN;
    float* out_if = out_vf + BN;

    const size_t sbuf_bytes = (size_t)2 * BN * sizeof(u64);      // 64 KiB tagged spike dbuf
    u64* sbuf     = (u64*)d_ws;
    unsigned* bar = (unsigned*)((char*)d_ws + sbuf_bytes);
    float* wT     = (float*)((char*)d_ws + sbuf_bytes + 256);

    const size_t need = sbuf_bytes + 256 + (size_t)BN * BN * sizeof(float);
    const bool tr = (ws_size >= need);

    // zero spike tags + barrier counter (captured into the graph, so every replay resets)
    hipMemsetAsync(d_ws, 0, sbuf_bytes + 256, stream);

    if (tr) {
        glif_kernel<true><<<NBLK, NTHR, 0, stream>>>(
            x_seq, w, b, v0, Ia0, vth, vrst, vrest, cm, tau, k, asc, mask,
            out_s, out_v, out_vf, out_if, sbuf, bar, wT);
    } else {
        glif_kernel<false><<<NBLK, NTHR, 0, stream>>>(
            x_seq, w, b, v0, Ia0, vth, vrst, vrest, cm, tau, k, asc, mask,
            out_s, out_v, out_vf, out_if, sbuf, bar, (float*)w);
    }
}

// Round 2
// 3280.756 us; speedup vs baseline: 3.0152x; 3.0152x over previous
//
#include <hip/hip_runtime.h>
#include <math.h>

#define TSTEPS 512
#define BN 4096
#define NBLK 128
#define NTHR 256
#define NPB 32        // neurons per block (BN/NBLK)
#define NW  128       // mask words per step (= NBLK), 32 spike bits each

typedef unsigned long long u64;

__device__ __forceinline__ u64 ld_agent(const u64* p) {
    return __hip_atomic_load(p, __ATOMIC_RELAXED, __HIP_MEMORY_SCOPE_AGENT);
}
__device__ __forceinline__ void st_agent(u64* p, u64 v) {
    __hip_atomic_store(p, v, __ATOMIC_RELAXED, __HIP_MEMORY_SCOPE_AGENT);
}

// Persistent kernel, 128 blocks (<=1/CU, co-resident). Per step each block
// publishes ONE tagged u64: (tag = t+1)<<32 | 32-bit spike mask of its neurons.
// Consumers poll 128 words (1 word/thread), rebuild a compacted active-column
// list deterministically (wave prefix scan, no atomics), then branch-free
// sparse GEMV over active columns of the transposed weights.
template<bool TR>
__global__ __launch_bounds__(NTHR, 1)
void glif_kernel(const float* __restrict__ x_seq, const float* __restrict__ w,
                 const float* __restrict__ b_in, const float* __restrict__ v0,
                 const float* __restrict__ Ia0, const float* __restrict__ vth_in,
                 const float* __restrict__ vrst_in, const float* __restrict__ vrest_in,
                 const float* __restrict__ cm_in, const float* __restrict__ tau_in,
                 const float* __restrict__ k_in, const float* __restrict__ asc_in,
                 const float* __restrict__ mask_in,
                 float* __restrict__ out_s, float* __restrict__ out_v,
                 float* __restrict__ out_vf, float* __restrict__ out_if,
                 u64* __restrict__ sbuf, unsigned* __restrict__ bar,
                 float* __restrict__ wT)
{
    __shared__ float tile[64][65];     // transpose staging (phase 0 only)
    __shared__ float maskf[BN];        // mask_in values (spike amplitudes)
    __shared__ int   list[BN];         // compacted active column indices
    __shared__ float partial[8][32];   // per-group GEMV partials
    __shared__ int   sc_total;
    __shared__ int   wsum;             // wave-0 scan total

    const int blk = blockIdx.x;
    const int tid = threadIdx.x;
    const int n0 = blk * NPB;

    // ---- Phase 0: transpose w -> wT (active columns become contiguous rows)
    if (TR) {
        for (int tt = 0; tt < 32; ++tt) {
            int tile_id = blk + tt * NBLK;       // 4096 tiles of 64x64
            int ti = tile_id >> 6, tj = tile_id & 63;
            int c = tid & 63, r0 = tid >> 6;
#pragma unroll
            for (int rr = 0; rr < 16; ++rr) {
                int r = r0 + rr * 4;
                tile[r][c] = w[(size_t)(ti * 64 + r) * BN + tj * 64 + c];
            }
            __syncthreads();
            int rw = tid & 63, c0 = tid >> 6;
#pragma unroll
            for (int cc = 0; cc < 16; ++cc) {
                int cw = c0 + cc * 4;
                wT[(size_t)(tj * 64 + cw) * BN + ti * 64 + rw] = tile[rw][cw];
            }
            __syncthreads();
        }
    }

    // stage spike amplitudes (mask_in) in LDS
    for (int i = tid; i < BN; i += NTHR) maskf[i] = mask_in[i];

    // ---- single grid barrier: wT complete before step loop
    __syncthreads();
    if (tid == 0) {
        __threadfence();
        __hip_atomic_fetch_add(bar, 1u, __ATOMIC_ACQ_REL, __HIP_MEMORY_SCOPE_AGENT);
        while (__hip_atomic_load(bar, __ATOMIC_RELAXED, __HIP_MEMORY_SCOPE_AGENT) < NBLK) {
            __builtin_amdgcn_s_sleep(8);
        }
        __threadfence();
    }
    __syncthreads();

    // ---- per-neuron state in registers (threads tid<NPB own neuron n)
    const int n = n0 + tid;
    float v = 0, I0 = 0, I1 = 0, bb = 0, aa = 0, bd0 = 0, bd1 = 0, as0 = 0, as1 = 0,
          vth = 0, vrst = 0, vrest = 0, cm = 1, tau = 1, msk = 0;
    if (tid < NPB) {
        v = v0[n]; I0 = Ia0[2 * n]; I1 = Ia0[2 * n + 1];
        bb = b_in[n]; vth = vth_in[n]; vrst = vrst_in[n]; vrest = vrest_in[n];
        cm = cm_in[n]; tau = tau_in[n]; msk = mask_in[n];
        aa  = (float)exp((double)(-1.0f / tau));
        bd0 = (float)exp((double)(-k_in[2 * n]));
        bd1 = (float)exp((double)(-k_in[2 * n + 1]));
        as0 = asc_in[2 * n]; as1 = asc_in[2 * n + 1];
    }

    const int g = tid >> 5, nl = tid & 31;

    for (int t = 0; t < TSTEPS; ++t) {
        float xt = 0.0f;
        if (tid < NPB) xt = x_seq[(size_t)t * BN + n];   // issue early

        // ---- poll this step's 128 mask words (1 per thread)
        const u64* src = sbuf + (size_t)(t & 1) * NW;
        unsigned m = 0;
        if (tid < NW) {
            u64 e = ld_agent(&src[tid]);
            while ((unsigned)(e >> 32) != (unsigned)t) {
                __builtin_amdgcn_s_sleep(1);
                e = ld_agent(&src[tid]);
            }
            m = (unsigned)e;
        }

        // ---- deterministic compaction: wave prefix scan of popcounts
        int c = __popc(m);
        int x = c;
#pragma unroll
        for (int d = 1; d < 64; d <<= 1) {
            int y = __shfl_up(x, d);
            if ((tid & 63) >= d) x += y;
        }
        if (tid == 63) wsum = x;
        __syncthreads();
        int inc = x + ((tid >= 64 && tid < NW) ? wsum : 0);
        if (tid == NW - 1) sc_total = inc;
        if (tid < NW) {
            int base = inc - c;
            unsigned mm = m;
            while (mm) {
                int bpos = __ffs(mm) - 1;
                mm &= mm - 1;
                list[base++] = (tid << 5) + bpos;
            }
        }
        __syncthreads();
        const int total = sc_total;

        // ---- branch-free sparse GEMV: 8 groups x 32 neurons
        float acc = 0.f;
        if (TR) {
            const float* wb = wT + n0 + nl;
#pragma unroll 4
            for (int i = g; i < total; i += 8) {
                int j = list[i];
                acc = fmaf(wb[(size_t)j * BN], maskf[j], acc);
            }
        } else {
            const float* wr = w + (size_t)(n0 + nl) * BN;
#pragma unroll 4
            for (int i = g; i < total; i += 8) {
                int j = list[i];
                acc = fmaf(wr[j], maskf[j], acc);
            }
        }
        partial[g][nl] = acc;
        __syncthreads();

        // ---- neuron update (reference op order), publish one tagged word
        float s = 0.0f;
        if (tid < NPB) {
            float lin = ((partial[0][tid] + partial[1][tid]) + (partial[2][tid] + partial[3][tid]))
                      + ((partial[4][tid] + partial[5][tid]) + (partial[6][tid] + partial[7][tid]));
            float xx = (xt + bb) + lin;
            float Isum = I0 + I1;
            float vinf = vrest + (tau * (xx + Isum)) / cm;
            float vp = vinf + (v - vinf) * aa;
            float uu = (vp - vth) / (vth - vrst);
            s = (uu > 0.0f) ? msk : 0.0f;
            float vpost = vp - (vp - vrst) * s;       // HARD_RESET
            I0 = I0 * bd0 + as0 * s;
            I1 = I1 * bd1 + as1 * s;
            v = vpost;
            out_s[(size_t)t * BN + n] = s;
            out_v[(size_t)t * BN + n] = vpost;
        }
        u64 bal = __ballot(s != 0.0f);                 // bits 0..31 from wave 0
        if (tid == 0) {
            u64 ent = (((u64)(t + 1)) << 32) | (u64)(unsigned)bal;
            st_agent(&sbuf[(size_t)((t + 1) & 1) * NW + blk], ent);
        }
        // no end-of-loop barrier needed: next iteration's first LDS write is
        // preceded by a __syncthreads that all update-readers must also reach.
    }

    if (tid < NPB) {
        out_vf[n] = v;
        out_if[2 * n] = I0;
        out_if[2 * n + 1] = I1;
    }
}

extern "C" void kernel_launch(void* const* d_in, const int* in_sizes, int n_in,
                              void* d_out, int out_size, void* d_ws, size_t ws_size,
                              hipStream_t stream)
{
    const float* x_seq = (const float*)d_in[0];
    const float* w     = (const float*)d_in[1];
    const float* b     = (const float*)d_in[2];
    const float* v0    = (const float*)d_in[3];
    const float* Ia0   = (const float*)d_in[4];
    const float* vth   = (const float*)d_in[5];
    const float* vrst  = (const float*)d_in[6];
    const float* vrest = (const float*)d_in[7];
    const float* cm    = (const float*)d_in[8];
    const float* tau   = (const float*)d_in[9];
    const float* k     = (const float*)d_in[10];
    const float* asc   = (const float*)d_in[11];
    const float* mask  = (const float*)d_in[12];

    float* out_s  = (float*)d_out;
    float* out_v  = out_s + (size_t)TSTEPS * BN;
    float* out_vf = out_v + (size_t)TSTEPS * BN;
    float* out_if = out_vf + BN;

    u64* sbuf     = (u64*)d_ws;                          // 2 x 128 tagged words (2 KiB)
    unsigned* bar = (unsigned*)((char*)d_ws + 2048);
    float* wT     = (float*)((char*)d_ws + 4096);

    const size_t need = 4096 + (size_t)BN * BN * sizeof(float);
    const bool tr = (ws_size >= need);

    // zero spike tags + barrier counter (inside graph -> resets every replay)
    hipMemsetAsync(d_ws, 0, 4096, stream);

    if (tr) {
        glif_kernel<true><<<NBLK, NTHR, 0, stream>>>(
            x_seq, w, b, v0, Ia0, vth, vrst, vrest, cm, tau, k, asc, mask,
            out_s, out_v, out_vf, out_if, sbuf, bar, wT);
    } else {
        glif_kernel<false><<<NBLK, NTHR, 0, stream>>>(
            x_seq, w, b, v0, Ia0, vth, vrst, vrest, cm, tau, k, asc, mask,
            out_s, out_v, out_vf, out_if, sbuf, bar, (float*)w);
    }
}

// Round 3
// 1738.346 us; speedup vs baseline: 5.6906x; 1.8873x over previous
//
#include <hip/hip_runtime.h>
#include <math.h>

#define TSTEPS 512
#define BN 4096
#define NBLK 128
#define NTHR 256
#define NPB 32        // neurons per block (BN/NBLK)
#define NW  128       // mask words per step (= NBLK), 32 spike bits each

typedef unsigned long long u64;

__device__ __forceinline__ u64 ld_agent(const u64* p) {
    return __hip_atomic_load(p, __ATOMIC_RELAXED, __HIP_MEMORY_SCOPE_AGENT);
}
__device__ __forceinline__ void st_agent(u64* p, u64 v) {
    __hip_atomic_store(p, v, __ATOMIC_RELAXED, __HIP_MEMORY_SCOPE_AGENT);
}

// Persistent kernel, 128 blocks (1/CU class, co-resident). Per step each block
// publishes ONE tagged u64 spike word. Wave 0 polls all 128 words (2/lane),
// builds a compacted active-column list with a single-wave prefix scan (no
// extra barriers), then all 256 threads do a deeply-pipelined gather-GEMV:
// 8 threads per active column, float4 each, 8 columns-rounds in flight.
// Only 2 __syncthreads per step.
template<bool TR>
__global__ __launch_bounds__(NTHR, 1)
void glif_kernel(const float* __restrict__ x_seq, const float* __restrict__ w,
                 const float* __restrict__ b_in, const float* __restrict__ v0,
                 const float* __restrict__ Ia0, const float* __restrict__ vth_in,
                 const float* __restrict__ vrst_in, const float* __restrict__ vrest_in,
                 const float* __restrict__ cm_in, const float* __restrict__ tau_in,
                 const float* __restrict__ k_in, const float* __restrict__ asc_in,
                 const float* __restrict__ mask_in,
                 float* __restrict__ out_s, float* __restrict__ out_v,
                 float* __restrict__ out_vf, float* __restrict__ out_if,
                 u64* __restrict__ sbuf, unsigned* __restrict__ bar,
                 float* __restrict__ wT)
{
    __shared__ float  tile[64][65];    // transpose staging (phase 0 only)
    __shared__ float  maskf[BN];       // spike amplitudes
    __shared__ int    list[BN];        // compacted active column indices
    __shared__ float4 wpart4[4][8];    // per-wave GEMV partials (flat: [4][32] floats)
    __shared__ int    sc_total;

    const int blk = blockIdx.x;
    const int tid = threadIdx.x;
    const int n0 = blk * NPB;
    const int wave = tid >> 6;
    const int lane = tid & 63;

    // ---- Phase 0: transpose w -> wT (active columns become contiguous rows)
    if (TR) {
        for (int tt = 0; tt < 32; ++tt) {
            int tile_id = blk + tt * NBLK;       // 4096 tiles of 64x64
            int ti = tile_id >> 6, tj = tile_id & 63;
            int c = tid & 63, r0 = tid >> 6;
#pragma unroll
            for (int rr = 0; rr < 16; ++rr) {
                int r = r0 + rr * 4;
                tile[r][c] = w[(size_t)(ti * 64 + r) * BN + tj * 64 + c];
            }
            __syncthreads();
            int rw = tid & 63, c0 = tid >> 6;
#pragma unroll
            for (int cc = 0; cc < 16; ++cc) {
                int cw = c0 + cc * 4;
                wT[(size_t)(tj * 64 + cw) * BN + ti * 64 + rw] = tile[rw][cw];
            }
            __syncthreads();
        }
    }

    // stage spike amplitudes in LDS
    for (int i = tid; i < BN; i += NTHR) maskf[i] = mask_in[i];

    // ---- single grid barrier: wT complete before step loop
    __syncthreads();
    if (tid == 0) {
        __threadfence();
        __hip_atomic_fetch_add(bar, 1u, __ATOMIC_ACQ_REL, __HIP_MEMORY_SCOPE_AGENT);
        while (__hip_atomic_load(bar, __ATOMIC_RELAXED, __HIP_MEMORY_SCOPE_AGENT) < NBLK) {
            __builtin_amdgcn_s_sleep(8);
        }
        __threadfence();
    }
    __syncthreads();

    // ---- per-neuron state in registers (threads tid<NPB own neuron n)
    const int n = n0 + tid;
    float v = 0, I0 = 0, I1 = 0, bb = 0, aa = 0, bd0 = 0, bd1 = 0, as0 = 0, as1 = 0,
          vth = 0, vrst = 0, vrest = 0, cm = 1, tau = 1, msk = 0;
    if (tid < NPB) {
        v = v0[n]; I0 = Ia0[2 * n]; I1 = Ia0[2 * n + 1];
        bb = b_in[n]; vth = vth_in[n]; vrst = vrst_in[n]; vrest = vrest_in[n];
        cm = cm_in[n]; tau = tau_in[n]; msk = mask_in[n];
        aa  = (float)exp((double)(-1.0f / tau));
        bd0 = (float)exp((double)(-k_in[2 * n]));
        bd1 = (float)exp((double)(-k_in[2 * n + 1]));
        as0 = asc_in[2 * n]; as1 = asc_in[2 * n + 1];
    }

    const int cslot = tid >> 3;          // 0..31: column slot within a round
    const int lane8 = tid & 7;           // 8 threads per column, float4 each
    const float* wb4 = wT + n0 + lane8 * 4;

    for (int t = 0; t < TSTEPS; ++t) {
        float xt = 0.0f;
        if (tid < NPB) xt = x_seq[(size_t)t * BN + n];   // issue early

        // ---- wave 0: poll 2 words per lane, single-wave scan, build list
        if (wave == 0) {
            const u64* src = sbuf + (size_t)(t & 1) * NW;
            u64 e0 = ld_agent(&src[2 * lane]);
            u64 e1 = ld_agent(&src[2 * lane + 1]);
            while ((unsigned)(e0 >> 32) != (unsigned)t) {
                __builtin_amdgcn_s_sleep(1);
                e0 = ld_agent(&src[2 * lane]);
            }
            while ((unsigned)(e1 >> 32) != (unsigned)t) {
                __builtin_amdgcn_s_sleep(1);
                e1 = ld_agent(&src[2 * lane + 1]);
            }
            unsigned m0 = (unsigned)e0, m1 = (unsigned)e1;
            int c0 = __popc(m0), c1 = __popc(m1);
            int x = c0 + c1;
#pragma unroll
            for (int d = 1; d < 64; d <<= 1) {
                int y = __shfl_up(x, d);
                if (lane >= d) x += y;
            }
            if (lane == 63) sc_total = x;
            int b0 = x - c1 - c0;                 // base for word 2*lane
            int b1 = x - c1;                      // base for word 2*lane+1
            while (m0) { int bp = __ffs(m0) - 1; m0 &= m0 - 1; list[b0++] = (lane << 6) + bp; }
            while (m1) { int bp = __ffs(m1) - 1; m1 &= m1 - 1; list[b1++] = (lane << 6) + 32 + bp; }
        }
        __syncthreads();                          // barrier 1: list + sc_total ready
        const int total = sc_total;

        // ---- pipelined gather-GEMV: 32 columns/round, 8-deep batches
        float4 acc = make_float4(0.f, 0.f, 0.f, 0.f);
        const int R = (total + 31) >> 5;          // rounds of 32 columns
        if (TR) {
            for (int r = 0; r < R; r += 8) {
#pragma unroll
                for (int u = 0; u < 8; ++u) {
                    int idx = (r + u) * 32 + cslot;
                    bool p = idx < total;
                    int j = list[p ? idx : 0];
                    float sj = p ? maskf[j] : 0.0f;
                    const float4 wv = *reinterpret_cast<const float4*>(wb4 + ((size_t)j << 12));
                    acc.x = fmaf(wv.x, sj, acc.x);
                    acc.y = fmaf(wv.y, sj, acc.y);
                    acc.z = fmaf(wv.z, sj, acc.z);
                    acc.w = fmaf(wv.w, sj, acc.w);
                }
            }
        } else {
            const float* r0p = w + (size_t)(n0 + lane8 * 4) * BN;
            for (int r = 0; r < R; r += 4) {
#pragma unroll
                for (int u = 0; u < 4; ++u) {
                    int idx = (r + u) * 32 + cslot;
                    bool p = idx < total;
                    int j = list[p ? idx : 0];
                    float sj = p ? maskf[j] : 0.0f;
                    acc.x = fmaf(r0p[j], sj, acc.x);
                    acc.y = fmaf(r0p[j + (size_t)BN], sj, acc.y);
                    acc.z = fmaf(r0p[j + 2 * (size_t)BN], sj, acc.z);
                    acc.w = fmaf(r0p[j + 3 * (size_t)BN], sj, acc.w);
                }
            }
        }
        // reduce across the 8 column-slots within each wave (lanes differing in bits 3..5)
#pragma unroll
        for (int d = 8; d < 64; d <<= 1) {
            acc.x += __shfl_xor(acc.x, d);
            acc.y += __shfl_xor(acc.y, d);
            acc.z += __shfl_xor(acc.z, d);
            acc.w += __shfl_xor(acc.w, d);
        }
        if (lane < 8) wpart4[wave][lane] = acc;   // lane == lane8 here
        __syncthreads();                          // barrier 2: partials ready

        // ---- neuron update; publish spike word ASAP, then finish state/stores
        float s = 0.0f;
        float vp = 0.0f;
        if (tid < NPB) {
            const float* wp = reinterpret_cast<const float*>(wpart4);  // [4][32]
            float lin = (wp[tid] + wp[32 + tid]) + (wp[64 + tid] + wp[96 + tid]);
            float xx = (xt + bb) + lin;
            float Isum = I0 + I1;
            float vinf = vrest + (tau * (xx + Isum)) / cm;
            vp = vinf + (v - vinf) * aa;
            float uu = (vp - vth) / (vth - vrst);
            s = (uu > 0.0f) ? msk : 0.0f;
        }
        u64 bal = __ballot(s != 0.0f);            // bits 0..31 valid in wave 0
        if (tid == 0) {
            u64 ent = (((u64)(t + 1)) << 32) | (u64)(unsigned)bal;
            st_agent(&sbuf[(size_t)((t + 1) & 1) * NW + blk], ent);
        }
        if (tid < NPB) {
            float vpost = vp - (vp - vrst) * s;   // HARD_RESET
            I0 = I0 * bd0 + as0 * s;
            I1 = I1 * bd1 + as1 * s;
            v = vpost;
            out_s[(size_t)t * BN + n] = s;
            out_v[(size_t)t * BN + n] = vpost;
        }
    }

    if (tid < NPB) {
        out_vf[n] = v;
        out_if[2 * n] = I0;
        out_if[2 * n + 1] = I1;
    }
}

extern "C" void kernel_launch(void* const* d_in, const int* in_sizes, int n_in,
                              void* d_out, int out_size, void* d_ws, size_t ws_size,
                              hipStream_t stream)
{
    const float* x_seq = (const float*)d_in[0];
    const float* w     = (const float*)d_in[1];
    const float* b     = (const float*)d_in[2];
    const float* v0    = (const float*)d_in[3];
    const float* Ia0   = (const float*)d_in[4];
    const float* vth   = (const float*)d_in[5];
    const float* vrst  = (const float*)d_in[6];
    const float* vrest = (const float*)d_in[7];
    const float* cm    = (const float*)d_in[8];
    const float* tau   = (const float*)d_in[9];
    const float* k     = (const float*)d_in[10];
    const float* asc   = (const float*)d_in[11];
    const float* mask  = (const float*)d_in[12];

    float* out_s  = (float*)d_out;
    float* out_v  = out_s + (size_t)TSTEPS * BN;
    float* out_vf = out_v + (size_t)TSTEPS * BN;
    float* out_if = out_vf + BN;

    u64* sbuf     = (u64*)d_ws;                          // 2 x 128 tagged words (2 KiB)
    unsigned* bar = (unsigned*)((char*)d_ws + 2048);
    float* wT     = (float*)((char*)d_ws + 4096);

    const size_t need = 4096 + (size_t)BN * BN * sizeof(float);
    const bool tr = (ws_size >= need);

    // zero spike tags + barrier counter (inside graph -> resets every replay)
    hipMemsetAsync(d_ws, 0, 4096, stream);

    if (tr) {
        glif_kernel<true><<<NBLK, NTHR, 0, stream>>>(
            x_seq, w, b, v0, Ia0, vth, vrst, vrest, cm, tau, k, asc, mask,
            out_s, out_v, out_vf, out_if, sbuf, bar, wT);
    } else {
        glif_kernel<false><<<NBLK, NTHR, 0, stream>>>(
            x_seq, w, b, v0, Ia0, vth, vrst, vrest, cm, tau, k, asc, mask,
            out_s, out_v, out_vf, out_if, sbuf, bar, (float*)w);
    }
}